// Round 1
// baseline (4487.560 us; speedup 1.0000x reference)
//
#include <hip/hip_runtime.h>
#include <float.h>
#include <math.h>

namespace {

constexpr int BB = 4;
constexpr int NP = 2048;
constexpr int KK = 20;
constexpr float NEGS = 0.2f;
constexpr float BEPS = 1e-5f;

__device__ inline float wmax(float v){
  #pragma unroll
  for(int m=32;m>=1;m>>=1) v = fmaxf(v, __shfl_xor(v, m, 64));
  return v;
}
__device__ inline float wsum(float v){
  #pragma unroll
  for(int m=32;m>=1;m>>=1) v += __shfl_xor(v, m, 64);
  return v;
}

// mean of x over N per (b,coord): 12 blocks
__global__ void k_meanx(const float* __restrict__ x, float* __restrict__ meanx){
  int bc = blockIdx.x;
  const float* p = x + (size_t)bc*NP;
  float s=0.f;
  for(int n=threadIdx.x;n<NP;n+=256) s+=p[n];
  __shared__ float red[256];
  red[threadIdx.x]=s; __syncthreads();
  for(int st=128;st>0;st>>=1){ if(threadIdx.x<st) red[threadIdx.x]+=red[threadIdx.x+st]; __syncthreads(); }
  if(threadIdx.x==0) meanx[bc]=red[0]/(float)NP;
}

// f = [p, p-mean, p*p, |p|] : (B,10,N)
__global__ void k_repsurf(const float* __restrict__ x, const float* __restrict__ meanx, float* __restrict__ f){
  int t=blockIdx.x*256+threadIdx.x;
  if(t>=BB*NP) return;
  int b=t/NP, n=t%NP;
  float p0=x[(b*3+0)*NP+n], p1=x[(b*3+1)*NP+n], p2=x[(b*3+2)*NP+n];
  float c0=p0-meanx[b*3+0], c1=p1-meanx[b*3+1], c2=p2-meanx[b*3+2];
  float r=sqrtf(p0*p0+p1*p1+p2*p2);
  float* fb=f+(size_t)b*10*NP+n;
  fb[0]=p0; fb[NP]=p1; fb[2*NP]=p2;
  fb[3*NP]=c0; fb[4*NP]=c1; fb[5*NP]=c2;
  fb[6*NP]=p0*p0; fb[7*NP]=p1*p1; fb[8*NP]=p2*p2;
  fb[9*NP]=r;
}

__global__ void k_sqnorm(const float* __restrict__ x, float* __restrict__ sq, int C){
  int t=blockIdx.x*256+threadIdx.x;
  if(t>=BB*NP)return;
  int b=t/NP, n=t%NP;
  float s=0.f;
  for(int c=0;c<C;c++){ float v=x[((size_t)b*C+c)*NP+n]; s+=v*v; }
  sq[t]=s;
}

// block per (b,i): full distance row + iterative top-20 argmin (tie -> lower index,
// matching jax.lax.top_k stability).
template<int C>
__global__ __launch_bounds__(256) void k_knn(const float* __restrict__ x, const float* __restrict__ sq, int* __restrict__ idx){
  __shared__ float xi[C];
  __shared__ float dist[NP];
  __shared__ float rv[256];
  __shared__ int ri[256];
  int b=blockIdx.x/NP, i=blockIdx.x%NP;
  const float* xb=x+(size_t)b*C*NP;
  for(int c=threadIdx.x;c<C;c+=256) xi[c]=xb[c*NP+i];
  __syncthreads();
  float sqi=sq[b*NP+i];
  for(int j=threadIdx.x;j<NP;j+=256){
    float dot=0.f;
    #pragma unroll 4
    for(int c=0;c<C;c++) dot += xb[c*NP+j]*xi[c];
    dist[j]=sqi-2.f*dot+sq[b*NP+j];
  }
  __syncthreads();
  int* out=idx+((size_t)b*NP+i)*KK;
  for(int kk=0;kk<KK;kk++){
    float bv=FLT_MAX; int bi=0x7fffffff;
    for(int j=threadIdx.x;j<NP;j+=256){
      float v=dist[j];
      if(v<bv){ bv=v; bi=j; }       // ascending j -> first (lowest) index kept on ties
    }
    rv[threadIdx.x]=bv; ri[threadIdx.x]=bi;
    __syncthreads();
    for(int st=128;st>0;st>>=1){
      if(threadIdx.x<st){
        float v2=rv[threadIdx.x+st]; int i2=ri[threadIdx.x+st];
        if(v2<rv[threadIdx.x] || (v2==rv[threadIdx.x] && i2<ri[threadIdx.x])){ rv[threadIdx.x]=v2; ri[threadIdx.x]=i2; }
      }
      __syncthreads();
    }
    if(threadIdx.x==0){ out[kk]=ri[0]; dist[ri[0]]=FLT_MAX; }
    __syncthreads();
  }
}

__global__ void k_nbmax(const float* __restrict__ x, const int* __restrict__ idx, float* __restrict__ nbm, int C){
  int t=blockIdx.x*256+threadIdx.x;
  if(t>=BB*C*NP)return;
  int n=t%NP; int bc=t/NP; int b=bc/C;
  const int* id=idx+((size_t)b*NP+n)*KK;
  const float* xr=x+(size_t)bc*NP;
  float m=-FLT_MAX;
  for(int k=0;k<KK;k++) m=fmaxf(m,xr[id[k]]);
  nbm[t]=m;
}

// gf = relu(Wfn @ [x; nbmax])  (B,512,N)
__global__ void k_gf(const float* __restrict__ x, const float* __restrict__ nbm, const float* __restrict__ wfn, float* __restrict__ gf, int C){
  int n=blockIdx.x*256+threadIdx.x;
  int o=blockIdx.y, b=blockIdx.z;
  const float* w=wfn+(size_t)o*2*C;
  float s=0.f;
  for(int c=0;c<C;c++) s+=w[c]*x[((size_t)b*C+c)*NP+n];
  for(int c=0;c<C;c++) s+=w[C+c]*nbm[((size_t)b*C+c)*NP+n];
  gf[((size_t)b*512+o)*NP+n]=fmaxf(s,0.f);
}

// gpart = Wec[:,2C:2C+512] @ gf  (k-independent part of edge conv)
__global__ void k_gpart(const float* __restrict__ gf, const float* __restrict__ wec, float* __restrict__ gp, int C2, int Cin, int Cout){
  int n=blockIdx.x*256+threadIdx.x;
  int o=blockIdx.y, b=blockIdx.z;
  const float* w=wec+(size_t)o*Cin+C2;
  float s=0.f;
  for(int c=0;c<512;c++) s+=w[c]*gf[((size_t)b*512+c)*NP+n];
  gp[((size_t)b*Cout+o)*NP+n]=s;
}

// block per (b,n): attention edge conv. Produces ymax/ymin over k and BN sum/sumsq (atomics).
template<int C, int Cout>
__global__ __launch_bounds__(256) void k_edge(
    const float* __restrict__ x, const int* __restrict__ idx,
    const float* __restrict__ wa1, const float* __restrict__ wa2,
    const float* __restrict__ wec, const float* __restrict__ gp,
    float* __restrict__ ymaxb, float* __restrict__ yminb,
    float* __restrict__ sumb, float* __restrict__ ssqb){
  constexpr int Cin=2*C+512;
  constexpr int NG=256/Cout;     // 4,4,2,1
  constexpr int KPT=KK/NG;       // 5,5,10,20
  __shared__ float xi[C];
  __shared__ float ee[KK][C];    // diff, then alpha*diff in place
  __shared__ float aa[KK][C];    // leaky(Wa1@diff + Wa2@xi)
  __shared__ float t3[Cout];
  __shared__ float rr[NG==1?1:4*NG*Cout];
  int b=blockIdx.x/NP, n=blockIdx.x%NP;
  int tid=threadIdx.x;
  const float* xb=x+(size_t)b*C*NP;
  for(int c=tid;c<C;c+=256) xi[c]=xb[c*NP+n];
  __syncthreads();
  // diff load
  const int* id=idx+((size_t)b*NP+n)*KK;
  for(int t=tid;t<KK*C;t+=256){
    int k=t/C, c=t%C;
    ee[k][c]=xb[c*NP+id[k]]-xi[c];
  }
  __syncthreads();
  // a[c][k] for all k, thread per channel c
  if(tid<C){
    const float* w2=wa2+(size_t)tid*C;
    float t2=0.f;
    for(int c=0;c<C;c++) t2+=w2[c]*xi[c];
    float ac[KK];
    #pragma unroll
    for(int k=0;k<KK;k++) ac[k]=t2;
    const float* w1=wa1+(size_t)tid*C;
    for(int c=0;c<C;c++){
      float wv=w1[c];
      #pragma unroll
      for(int k=0;k<KK;k++) ac[k]+=wv*ee[k][c];
    }
    #pragma unroll
    for(int k=0;k<KK;k++){ float v=ac[k]; aa[k][tid]=v>0.f?v:NEGS*v; }
  }
  __syncthreads();
  // softmax over channels per k; scale diff in place. wave per k.
  int wid=tid>>6, lane=tid&63;
  for(int k=wid;k<KK;k+=4){
    if constexpr (C<=64){
      float a = lane<C ? aa[k][lane] : -FLT_MAX;
      float mx=wmax(a);
      float p = lane<C ? __expf(a-mx) : 0.f;
      float sm=wsum(p);
      if(lane<C) ee[k][lane]=(p/sm)*ee[k][lane];
    } else {
      float a0=aa[k][lane], a1=aa[k][lane+64];
      float mx=wmax(fmaxf(a0,a1));
      float p0=__expf(a0-mx), p1=__expf(a1-mx);
      float sm=wsum(p0+p1);
      ee[k][lane]=(p0/sm)*ee[k][lane];
      ee[k][lane+64]=(p1/sm)*ee[k][lane+64];
    }
  }
  // t3[o] = Wec[o,C:2C] . xi + gpart
  if(tid<Cout){
    float s=gp[((size_t)b*Cout+tid)*NP+n];
    const float* w=wec+(size_t)tid*Cin+C;
    for(int c=0;c<C;c++) s+=w[c]*xi[c];
    t3[tid]=s;
  }
  __syncthreads();
  // y[o][k] = Wec[o,:C] . ee[k] + t3[o]; fold max/min/sum/sumsq over k
  int o=tid%Cout, g=tid/Cout;
  float acc[KPT];
  #pragma unroll
  for(int t=0;t<KPT;t++) acc[t]=0.f;
  const float* w=wec+(size_t)o*Cin;
  for(int c=0;c<C;c++){
    float wv=w[c];
    #pragma unroll
    for(int t=0;t<KPT;t++) acc[t]+=wv*ee[g+t*NG][c];
  }
  float t3o=t3[o];
  float mx=-FLT_MAX, mn=FLT_MAX, s=0.f, ss=0.f;
  #pragma unroll
  for(int t=0;t<KPT;t++){
    float y=acc[t]+t3o;
    mx=fmaxf(mx,y); mn=fminf(mn,y); s+=y; ss+=y*y;
  }
  if constexpr (NG==1){
    ymaxb[((size_t)b*Cout+o)*NP+n]=mx;
    yminb[((size_t)b*Cout+o)*NP+n]=mn;
    atomicAdd(&sumb[o],s);
    atomicAdd(&ssqb[o],ss);
  } else {
    rr[(0*NG+g)*Cout+o]=mx;
    rr[(1*NG+g)*Cout+o]=mn;
    rr[(2*NG+g)*Cout+o]=s;
    rr[(3*NG+g)*Cout+o]=ss;
    __syncthreads();
    if(g==0){
      for(int gg=1;gg<NG;gg++){
        mx=fmaxf(mx,rr[(0*NG+gg)*Cout+o]);
        mn=fminf(mn,rr[(1*NG+gg)*Cout+o]);
        s+=rr[(2*NG+gg)*Cout+o];
        ss+=rr[(3*NG+gg)*Cout+o];
      }
      ymaxb[((size_t)b*Cout+o)*NP+n]=mx;
      yminb[((size_t)b*Cout+o)*NP+n]=mn;
      atomicAdd(&sumb[o],s);
      atomicAdd(&ssqb[o],ss);
    }
  }
}

__global__ void k_bnprep(const float* __restrict__ sumb, const float* __restrict__ ssqb,
                         const float* __restrict__ gg, const float* __restrict__ bb,
                         float* __restrict__ sct, int Cout, float invcnt){
  int o=blockIdx.x*256+threadIdx.x;
  if(o>=Cout)return;
  float m=sumb[o]*invcnt;
  float v=ssqb[o]*invcnt-m*m;
  float s=gg[o]*rsqrtf(v+BEPS);
  sct[o]=s; sct[Cout+o]=bb[o]-s*m;
}

__global__ void k_stageout(const float* __restrict__ ymaxb, const float* __restrict__ yminb,
                           const float* __restrict__ sct, float* __restrict__ xo, int Cout){
  int t=blockIdx.x*256+threadIdx.x;
  if(t>=BB*Cout*NP)return;
  int o=(t/NP)%Cout;
  float s=sct[o], tt=sct[Cout+o];
  float y = s>=0.f ? fmaf(s,ymaxb[t],tt) : fmaf(s,yminb[t],tt);
  xo[t]=fmaxf(y,0.f);
}

__global__ void k_y5(const float* __restrict__ x1,const float* __restrict__ x2,const float* __restrict__ x3,const float* __restrict__ x4,
                     const float* __restrict__ w5, float* __restrict__ y5){
  int n=blockIdx.x*256+threadIdx.x;
  int o=blockIdx.y, b=blockIdx.z;
  const float* w=w5+(size_t)o*512;
  float s=0.f;
  for(int c=0;c<64;c++)  s+=w[c]     *x1[((size_t)b*64+c)*NP+n];
  for(int c=0;c<64;c++)  s+=w[64+c]  *x2[((size_t)b*64+c)*NP+n];
  for(int c=0;c<128;c++) s+=w[128+c] *x3[((size_t)b*128+c)*NP+n];
  for(int c=0;c<256;c++) s+=w[256+c] *x4[((size_t)b*256+c)*NP+n];
  y5[((size_t)b*1024+o)*NP+n]=s;
}

// per-channel BN stats over (B,N): block per channel
__global__ void k_stats(const float* __restrict__ y, const float* __restrict__ gg, const float* __restrict__ bb,
                        float* __restrict__ sct, int Cch){
  int o=blockIdx.x;
  float s=0.f, ss=0.f;
  for(int t=threadIdx.x;t<BB*NP;t+=256){
    int b=t/NP, n=t%NP;
    float v=y[((size_t)b*Cch+o)*NP+n];
    s+=v; ss+=v*v;
  }
  __shared__ float r1[256], r2[256];
  r1[threadIdx.x]=s; r2[threadIdx.x]=ss;
  __syncthreads();
  for(int st=128;st>0;st>>=1){
    if(threadIdx.x<st){ r1[threadIdx.x]+=r1[threadIdx.x+st]; r2[threadIdx.x]+=r2[threadIdx.x+st]; }
    __syncthreads();
  }
  if(threadIdx.x==0){
    float m=r1[0]/(float)(BB*NP);
    float v=r2[0]/(float)(BB*NP)-m*m;
    float sc=gg[o]*rsqrtf(v+BEPS);
    sct[o]=sc; sct[Cch+o]=bb[o]-sc*m;
  }
}

__global__ void k_gvec(const float* __restrict__ y5, const float* __restrict__ sct, float* __restrict__ gvec){
  int bo=blockIdx.x; int b=bo>>10, o=bo&1023;
  float sc=sct[o], sh=sct[1024+o];
  float m=-FLT_MAX;
  for(int n=threadIdx.x;n<NP;n+=256) m=fmaxf(m, fmaf(sc,y5[((size_t)b*1024+o)*NP+n],sh));
  __shared__ float r[256];
  r[threadIdx.x]=m; __syncthreads();
  for(int st=128;st>0;st>>=1){ if(threadIdx.x<st) r[threadIdx.x]=fmaxf(r[threadIdx.x],r[threadIdx.x+st]); __syncthreads(); }
  if(threadIdx.x==0) gvec[bo]=fmaxf(r[0],0.f);
}

__global__ void k_t6(const float* __restrict__ gvec, const float* __restrict__ w6, float* __restrict__ t6b){
  int t=blockIdx.x*256+threadIdx.x;
  if(t>=BB*512)return;
  int b=t/512, o=t%512;
  const float* w=w6+(size_t)o*1152+128;
  const float* gv=gvec+(size_t)b*1024;
  float s=0.f;
  for(int c=0;c<1024;c++) s+=w[c]*gv[c];
  t6b[t]=s;
}

__global__ void k_y6(const float* __restrict__ x3, const float* __restrict__ w6, const float* __restrict__ t6b, float* __restrict__ y6){
  int n=blockIdx.x*256+threadIdx.x;
  int o=blockIdx.y, b=blockIdx.z;
  const float* w=w6+(size_t)o*1152;
  float s=t6b[b*512+o];
  for(int c=0;c<128;c++) s+=w[c]*x3[((size_t)b*128+c)*NP+n];
  y6[((size_t)b*512+o)*NP+n]=s;
}

__global__ void k_norm(float* __restrict__ y, const float* __restrict__ sct, int Cch, int total){
  int t=blockIdx.x*256+threadIdx.x;
  if(t>=total)return;
  int o=(t/NP)%Cch;
  y[t]=fmaxf(fmaf(sct[o],y[t],sct[Cch+o]),0.f);
}

__global__ void k_lin(const float* __restrict__ xin, const float* __restrict__ w, float* __restrict__ yo, int Cin, int Co){
  int n=blockIdx.x*256+threadIdx.x;
  int o=blockIdx.y, b=blockIdx.z;
  const float* wr=w+(size_t)o*Cin;
  float s=0.f;
  for(int c=0;c<Cin;c++) s+=wr[c]*xin[((size_t)b*Cin+c)*NP+n];
  yo[((size_t)b*Co+o)*NP+n]=s;
}

__global__ void k_out(const float* __restrict__ h7, const float* __restrict__ w8, float* __restrict__ out){
  int n=blockIdx.x*256+threadIdx.x;
  int o=blockIdx.y, b=blockIdx.z;
  const float* wr=w8+(size_t)o*256;
  float s=0.f;
  for(int c=0;c<256;c++) s+=wr[c]*h7[((size_t)b*256+c)*NP+n];
  out[((size_t)b*50+o)*NP+n]=fmaxf(s,0.f);
}

} // namespace

extern "C" void kernel_launch(void* const* d_in, const int* in_sizes, int n_in,
                              void* d_out, int out_size, void* d_ws, size_t ws_size,
                              hipStream_t stream){
  const float* x   =(const float*)d_in[0];
  const float* wa_1[4]={(const float*)d_in[1],(const float*)d_in[3],(const float*)d_in[5],(const float*)d_in[7]};
  const float* wa_2[4]={(const float*)d_in[2],(const float*)d_in[4],(const float*)d_in[6],(const float*)d_in[8]};
  const float* wfn[4]={(const float*)d_in[9],(const float*)d_in[10],(const float*)d_in[11],(const float*)d_in[12]};
  const float* wec[4]={(const float*)d_in[13],(const float*)d_in[14],(const float*)d_in[15],(const float*)d_in[16]};
  const float* w5=(const float*)d_in[17];
  const float* w6=(const float*)d_in[18];
  const float* w7=(const float*)d_in[19];
  const float* w8=(const float*)d_in[20];
  const float* gs[7]; const float* bs[7];
  for(int i=0;i<7;i++){ gs[i]=(const float*)d_in[21+2*i]; bs[i]=(const float*)d_in[22+2*i]; }

  float* base=(float*)d_ws;
  size_t off=0;
  float* f_buf=base+off; off+=(size_t)10*BB*NP;
  float* x1=base+off;    off+=(size_t)64*BB*NP;
  float* x2=base+off;    off+=(size_t)64*BB*NP;
  float* x3=base+off;    off+=(size_t)128*BB*NP;
  float* x4=base+off;    off+=(size_t)256*BB*NP;
  float* sq=base+off;    off+=(size_t)BB*NP;
  int*   idxb=(int*)(base+off); off+=(size_t)BB*NP*KK;
  float* TMP=base+off;
  float* nbm=TMP;
  float* gfb=nbm+(size_t)256*BB*NP;
  float* gpb=gfb+(size_t)512*BB*NP;
  float* ymx=gpb+(size_t)256*BB*NP;
  float* ymn=ymx+(size_t)256*BB*NP;
  off += (size_t)1536*BB*NP;           // stage temps (12.58M floats), reused by y5/y6/y7
  float* sums=base+off;  off+=2048;
  float* sct=base+off;   off+=2048;
  float* gvecb=base+off; off+=(size_t)BB*1024;
  float* t6b=base+off;   off+=(size_t)BB*512;
  float* meanxb=base+off; off+=16;
  // aliases into the stage-temp region (stage temps are dead by the time these are used)
  float* y5=TMP;                              // 1024*BB*NP
  float* y6=TMP+(size_t)1024*BB*NP;           // 512*BB*NP
  float* y7=TMP;                              // 256*BB*NP, y5 dead by then

  hipMemsetAsync(sums,0,2048*sizeof(float),stream);

  k_meanx<<<12,256,0,stream>>>(x,meanxb);
  k_repsurf<<<(BB*NP+255)/256,256,0,stream>>>(x,meanxb,f_buf);

  const int Cs[4]={10,64,64,128};
  const int Co[4]={64,64,128,256};
  const float* xin[4]={f_buf,x1,x2,x3};
  float* xout[4]={x1,x2,x3,x4};

  for(int s=0;s<4;s++){
    int C=Cs[s], Cout=Co[s], Cin=2*C+512;
    k_sqnorm<<<(BB*NP+255)/256,256,0,stream>>>(xin[s],sq,C);
    if(C==10)      k_knn<10> <<<BB*NP,256,0,stream>>>(xin[s],sq,idxb);
    else if(s==1||s==2) k_knn<64> <<<BB*NP,256,0,stream>>>(xin[s],sq,idxb);
    else           k_knn<128><<<BB*NP,256,0,stream>>>(xin[s],sq,idxb);
    k_nbmax<<<(BB*C*NP+255)/256,256,0,stream>>>(xin[s],idxb,nbm,C);
    k_gf<<<dim3(NP/256,512,BB),256,0,stream>>>(xin[s],nbm,wfn[s],gfb,C);
    k_gpart<<<dim3(NP/256,Cout,BB),256,0,stream>>>(gfb,wec[s],gpb,2*C,Cin,Cout);
    float* sb=sums+(size_t)s*512; float* qb=sb+256;
    if(s==0)      k_edge<10,64 ><<<BB*NP,256,0,stream>>>(xin[s],idxb,wa_1[s],wa_2[s],wec[s],gpb,ymx,ymn,sb,qb);
    else if(s==1) k_edge<64,64 ><<<BB*NP,256,0,stream>>>(xin[s],idxb,wa_1[s],wa_2[s],wec[s],gpb,ymx,ymn,sb,qb);
    else if(s==2) k_edge<64,128><<<BB*NP,256,0,stream>>>(xin[s],idxb,wa_1[s],wa_2[s],wec[s],gpb,ymx,ymn,sb,qb);
    else          k_edge<128,256><<<BB*NP,256,0,stream>>>(xin[s],idxb,wa_1[s],wa_2[s],wec[s],gpb,ymx,ymn,sb,qb);
    k_bnprep<<<1,256,0,stream>>>(sb,qb,gs[s],bs[s],sct,Cout,1.f/(float)(BB*NP*KK));
    k_stageout<<<(BB*Cout*NP+255)/256,256,0,stream>>>(ymx,ymn,sct,xout[s],Cout);
  }

  k_y5<<<dim3(NP/256,1024,BB),256,0,stream>>>(x1,x2,x3,x4,w5,y5);
  k_stats<<<1024,256,0,stream>>>(y5,gs[4],bs[4],sct,1024);
  k_gvec<<<BB*1024,256,0,stream>>>(y5,sct,gvecb);
  k_t6<<<(BB*512+255)/256,256,0,stream>>>(gvecb,w6,t6b);
  k_y6<<<dim3(NP/256,512,BB),256,0,stream>>>(x3,w6,t6b,y6);
  k_stats<<<512,256,0,stream>>>(y6,gs[5],bs[5],sct,512);
  k_norm<<<(BB*512*NP+255)/256,256,0,stream>>>(y6,sct,512,BB*512*NP);
  k_lin<<<dim3(NP/256,256,BB),256,0,stream>>>(y6,w7,y7,512,256);
  k_stats<<<256,256,0,stream>>>(y7,gs[6],bs[6],sct,256);
  k_norm<<<(BB*256*NP+255)/256,256,0,stream>>>(y7,sct,256,BB*256*NP);
  k_out<<<dim3(NP/256,50,BB),256,0,stream>>>(y7,w8,(float*)d_out);

  (void)in_sizes; (void)n_in; (void)out_size; (void)ws_size;
}